// Round 2
// baseline (1117.505 us; speedup 1.0000x reference)
//
#include <hip/hip_runtime.h>
#include <hip/hip_bf16.h>

// SioConvNet on MI355X. Round 4: staging-VALU + serialization.
//  - Split-bf16 conversion now truncation-based (hi = trunc, lo = f-hi exact,
//    trunc): 4 VALU ops/elem vs ~9 for RNE x2. Net split error ~2^-16 rel.
//  - Bias folded into split-K atomic GEMMs at blockIdx.z==0 (no bias_bcast).
//  - Deeper split-K / smaller tiles on all mid GEMMs (>=1-2 blocks/CU).
//  - scan_p1+p2+p3 fused into one 2x1024 kernel (chunk combine via LDS).
//  - Vocab GEMM reads a pre-converted bf16 copy of tok_out_w (WBF path),
//    ws_size-guarded with fp32 fallback.
// Split-bf16 (hi+lo, 3-pass MFMA) retained on every GEMM feeding the recurrence
// (za phase sensitivity amplifies bf16-level error ~100x). Vocab GEMM single bf16.
// DEPTH=3, DIM=512, DFF=2048, DT=64, VOCAB=32000, B=2, L=512, M=B*L=1024.

#define LDIM 512
#define SEQL 512
#define DT_ 64
#define NC 16
#define CL 32
#define BK 32

typedef short s16x4 __attribute__((ext_vector_type(4)));
typedef short s16x8 __attribute__((ext_vector_type(8)));
typedef float f32x4 __attribute__((ext_vector_type(4)));

__device__ __forceinline__ unsigned short f2bf(float f) {  // RNE
  unsigned u = __builtin_bit_cast(unsigned, f);
  return (unsigned short)((u + 0x7fffu + ((u >> 16) & 1u)) >> 16);
}

// Truncation split: hi = f with low mantissa zeroed; lo = trunc16(f - hi).
__device__ __forceinline__ void split2(float f, short& hi, short& lo) {
  unsigned u = __builtin_bit_cast(unsigned, f);
  hi = (short)(u >> 16);
  float hf = __builtin_bit_cast(float, u & 0xFFFF0000u);
  float lf = f - hf;  // exact
  lo = (short)(__builtin_bit_cast(unsigned, lf) >> 16);
}

// C[M,N] = act(A[M,K] @ W[N,K]^T + bias) (+R). A, W row-major, K contiguous.
// ACT: 0=none, 1=silu (post-sum). ATOM: atomicAdd into C (split-K); bias applied
// only by blockIdx.z==0. SPL: split-bf16 hi/lo 3-pass MFMA (fp32-class).
// AACT: 1 = silu(A) while staging. WBF: W is pre-converted bf16 (shorts).
template <int BM, int BN, int ACT, bool RES, bool ATOM, bool BIAS, bool SPL,
          int AACT = 0, bool WBF = false>
__global__ __launch_bounds__(256) void gemm_bt(
    const float* __restrict__ A, const float* __restrict__ W,
    const float* __restrict__ bias, const float* __restrict__ R,
    float* __restrict__ C, int M, int N, int K, int kc) {
  constexpr int WM = BM / 2, WN = BN / 2, TM = WM / 16, TN = WN / 16;
  constexpr int LDA = BK + 8;  // rows 80B apart -> 16B-aligned, 2-way-bank (free)
  constexpr int PLANES = SPL ? 2 : 1;
  __shared__ __align__(16) short As[BM * LDA * PLANES];
  __shared__ __align__(16) short Bs[BN * LDA * PLANES];

  const int tid = threadIdx.x;
  const int wid = tid >> 6, lane = tid & 63;
  const int q = lane >> 4, l16 = lane & 15;
  const int wm = (wid >> 1) * WM, wn = (wid & 1) * WN;
  const int m0 = blockIdx.y * BM, n0 = blockIdx.x * BN;
  const int kbeg = blockIdx.z * kc;
  const int kend = min(K, kbeg + kc);

  f32x4 acc[TM][TN] = {};

  constexpr int AF = BM * BK / 1024;  // float4 loads per thread for A tile
  constexpr int BF = BN * BK / 1024;

  for (int k0 = kbeg; k0 < kend; k0 += BK) {
#pragma unroll
    for (int t = 0; t < AF; t++) {
      int fi = tid + t * 256;
      int row = fi >> 3, col = (fi & 7) << 2;
      float4 v = *(const float4*)(A + (size_t)(m0 + row) * K + k0 + col);
      float* vp = (float*)&v;
      s16x4 hv, lv;
#pragma unroll
      for (int c = 0; c < 4; c++) {
        if (AACT == 1) vp[c] = vp[c] / (1.f + __expf(-vp[c]));
        if (SPL) {
          short h_, l_;
          split2(vp[c], h_, l_);
          hv[c] = h_; lv[c] = l_;
        } else {
          hv[c] = (short)f2bf(vp[c]);
        }
      }
      *(s16x4*)(&As[row * LDA + col]) = hv;
      if (SPL) *(s16x4*)(&As[BM * LDA + row * LDA + col]) = lv;
    }
    if constexpr (WBF) {
      // W already bf16: pure 16B copies, zero conversion VALU.
      const short* Wb = (const short*)W;
      constexpr int BF2 = BN / 64;  // 16B chunks per thread (BN*BK/8/256)
#pragma unroll
      for (int t = 0; t < BF2; t++) {
        int fi = tid + t * 256;
        int row = fi >> 2, col8 = (fi & 3) << 3;
        s16x8 v = *(const s16x8*)(Wb + (size_t)(n0 + row) * K + k0 + col8);
        *(s16x8*)(&Bs[row * LDA + col8]) = v;
      }
    } else {
#pragma unroll
      for (int t = 0; t < BF; t++) {
        int fi = tid + t * 256;
        int row = fi >> 3, col = (fi & 7) << 2;
        float4 v = *(const float4*)(W + (size_t)(n0 + row) * K + k0 + col);
        const float* vp = (const float*)&v;
        s16x4 hv, lv;
#pragma unroll
        for (int c = 0; c < 4; c++) {
          if (SPL) {
            short h_, l_;
            split2(vp[c], h_, l_);
            hv[c] = h_; lv[c] = l_;
          } else {
            hv[c] = (short)f2bf(vp[c]);
          }
        }
        *(s16x4*)(&Bs[row * LDA + col]) = hv;
        if (SPL) *(s16x4*)(&Bs[BN * LDA + row * LDA + col]) = lv;
      }
    }
    __syncthreads();
    s16x8 ah[TM], bh[TN], al[TM], bl[TN];
#pragma unroll
    for (int i = 0; i < TM; i++) {
      ah[i] = *(const s16x8*)(&As[(wm + i * 16 + l16) * LDA + q * 8]);
      if (SPL) al[i] = *(const s16x8*)(&As[BM * LDA + (wm + i * 16 + l16) * LDA + q * 8]);
    }
#pragma unroll
    for (int j = 0; j < TN; j++) {
      bh[j] = *(const s16x8*)(&Bs[(wn + j * 16 + l16) * LDA + q * 8]);
      if (SPL) bl[j] = *(const s16x8*)(&Bs[BN * LDA + (wn + j * 16 + l16) * LDA + q * 8]);
    }
#pragma unroll
    for (int i = 0; i < TM; i++)
#pragma unroll
      for (int j = 0; j < TN; j++) {
        acc[i][j] = __builtin_amdgcn_mfma_f32_16x16x32_bf16(ah[i], bh[j], acc[i][j], 0, 0, 0);
        if (SPL) {
          acc[i][j] = __builtin_amdgcn_mfma_f32_16x16x32_bf16(ah[i], bl[j], acc[i][j], 0, 0, 0);
          acc[i][j] = __builtin_amdgcn_mfma_f32_16x16x32_bf16(al[i], bh[j], acc[i][j], 0, 0, 0);
        }
      }
    __syncthreads();
  }

#pragma unroll
  for (int i = 0; i < TM; i++)
#pragma unroll
    for (int j = 0; j < TN; j++)
#pragma unroll
      for (int r = 0; r < 4; r++) {
        int m = m0 + wm + i * 16 + q * 4 + r;
        int n = n0 + wn + j * 16 + l16;
        float v = acc[i][j][r];
        if (BIAS && kbeg == 0) v += bias[n];
        if (ACT == 1) v = v / (1.f + __expf(-v));
        if (RES) v += R[(size_t)m * N + n];
        if (ATOM) atomicAdd(&C[(size_t)m * N + n], v);
        else C[(size_t)m * N + n] = v;
      }
}

// Zero-fill (count divisible by 1024).
__global__ __launch_bounds__(256) void fill0(float* __restrict__ p) {
  size_t i = (size_t)(blockIdx.x * 256 + threadIdx.x) * 4;
  *(float4*)(p + i) = make_float4(0.f, 0.f, 0.f, 0.f);
}

// fp32 -> bf16 (RNE) streaming convert, 4 elems/thread.
__global__ __launch_bounds__(256) void cvt_rne(const float* __restrict__ src,
                                               short* __restrict__ dst) {
  size_t i = (size_t)(blockIdx.x * 256 + threadIdx.x) * 4;
  float4 v = *(const float4*)(src + i);
  const float* vp = (const float*)&v;
  s16x4 o;
#pragma unroll
  for (int c = 0; c < 4; c++) o[c] = (short)f2bf(vp[c]);
  *(s16x4*)(dst + i) = o;
}

// LayerNorm over last dim 512; one wave per row.
__global__ __launch_bounds__(256) void ln512(const float* __restrict__ x,
                                             const float* __restrict__ g,
                                             const float* __restrict__ b,
                                             float* __restrict__ o) {
  int wid = threadIdx.x >> 6, lane = threadIdx.x & 63;
  int row = blockIdx.x * 4 + wid;
  const float* xr = x + (size_t)row * 512 + lane * 8;
  float4 v0 = *(const float4*)xr;
  float4 v1 = *(const float4*)(xr + 4);
  float s = v0.x + v0.y + v0.z + v0.w + v1.x + v1.y + v1.z + v1.w;
  float ss = v0.x * v0.x + v0.y * v0.y + v0.z * v0.z + v0.w * v0.w +
             v1.x * v1.x + v1.y * v1.y + v1.z * v1.z + v1.w * v1.w;
#pragma unroll
  for (int m = 32; m; m >>= 1) { s += __shfl_xor(s, m); ss += __shfl_xor(ss, m); }
  float mean = s * (1.f / 512.f);
  float var = ss * (1.f / 512.f) - mean * mean;
  float rstd = rsqrtf(var + 1e-5f);
  const float* gp = g + lane * 8;
  const float* bp = b + lane * 8;
  float4 g0 = *(const float4*)gp, g1 = *(const float4*)(gp + 4);
  float4 b0 = *(const float4*)bp, b1 = *(const float4*)(bp + 4);
  float* op = o + (size_t)row * 512 + lane * 8;
  float4 r0, r1;
  r0.x = (v0.x - mean) * rstd * g0.x + b0.x;
  r0.y = (v0.y - mean) * rstd * g0.y + b0.y;
  r0.z = (v0.z - mean) * rstd * g0.z + b0.z;
  r0.w = (v0.w - mean) * rstd * g0.w + b0.w;
  r1.x = (v1.x - mean) * rstd * g1.x + b1.x;
  r1.y = (v1.y - mean) * rstd * g1.y + b1.y;
  r1.z = (v1.z - mean) * rstd * g1.z + b1.z;
  r1.w = (v1.w - mean) * rstd * g1.w + b1.w;
  *(float4*)op = r0;
  *(float4*)(op + 4) = r1;
}

// a[b,i,d] from za: a = za * rsqrt(|za|^2) * exp(-|za|^2)
__device__ __forceinline__ float2 a_of(const float* __restrict__ za, int b, int i, int d) {
  float zr = za[(size_t)(b * SEQL + i) * 128 + 2 * d];
  float zi = za[(size_t)(b * SEQL + i) * 128 + 2 * d + 1];
  float m2 = zr * zr + zi * zi;
  float sc = rsqrtf(m2) * __expf(-m2);
  return make_float2(zr * sc, zi * sc);
}

// xsm1[i]: 0 for i==0, h0c for i==1, u[i-2] (real) otherwise.
__device__ __forceinline__ float2 xsm1_of(const float* __restrict__ u,
                                          const float* __restrict__ h0,
                                          int b, int i, int d) {
  if (i == 0) return make_float2(0.f, 0.f);
  if (i == 1) return make_float2(h0[d * 2], h0[d * 2 + 1]);
  return make_float2(u[(size_t)(b * SEQL + i - 2) * DT_ + d], 0.f);
}

// Fused backward chunked scan (was scan_p1 + scan_p2 + scan_p3).
// One block per batch element b; 1024 threads = (chunk c = t>>6) x (d = t&63).
// p = real(h) * silu(y)   (y arrives PRE-activation).
__global__ __launch_bounds__(1024) void scan_all(const float* __restrict__ za,
                                                 const float* __restrict__ u,
                                                 const float* __restrict__ h0,
                                                 const float* __restrict__ y,
                                                 float* __restrict__ p) {
  __shared__ float2 sA[NC * 64], sB[NC * 64], sT[NC * 64];
  const int b = blockIdx.x;
  const int t = threadIdx.x;
  const int d = t & 63, c = t >> 6;  // c in [0,16)

  // Phase 1: per-chunk (A = prod a, Bv = backward eval with t_end = 0).
  float2 Aa = make_float2(1.f, 0.f), Bv = make_float2(0.f, 0.f);
  for (int i = c * CL + CL - 1; i >= c * CL; i--) {
    float2 a = a_of(za, b, i, d);
    float2 xs = xsm1_of(u, h0, b, i, d);
    float2 nb, nA;
    nb.x = xs.x + a.x * Bv.x - a.y * Bv.y;
    nb.y = xs.y + a.x * Bv.y + a.y * Bv.x;
    nA.x = a.x * Aa.x - a.y * Aa.y;
    nA.y = a.x * Aa.y + a.y * Aa.x;
    Bv = nb; Aa = nA;
  }
  sA[c * 64 + d] = Aa;
  sB[c * 64 + d] = Bv;
  __syncthreads();

  // Phase 2: serial backward combine over the NC chunks (64 threads active).
  if (c == 0) {
    float2 tt = make_float2(u[(size_t)(b * SEQL + SEQL - 2) * DT_ + d], 0.f);
    for (int cc = NC - 1; cc >= 0; cc--) {
      sT[cc * 64 + d] = tt;
      float2 A = sA[cc * 64 + d], Bc = sB[cc * 64 + d];
      float2 nt;
      nt.x = A.x * tt.x - A.y * tt.y + Bc.x;
      nt.y = A.x * tt.y + A.y * tt.x + Bc.y;
      tt = nt;
    }
  }
  __syncthreads();

  // Phase 3: redo chunk backward scan from known t_end; write p.
  float2 tt = sT[c * 64 + d];
  for (int i = c * CL + CL - 1; i >= c * CL; i--) {
    float2 a = a_of(za, b, i, d);
    float2 xs = xsm1_of(u, h0, b, i, d);
    float2 nt;
    nt.x = xs.x + a.x * tt.x - a.y * tt.y;
    nt.y = xs.y + a.x * tt.y + a.y * tt.x;
    tt = nt;
    float hr = tt.x;
    if (i == SEQL - 1) hr += u[(size_t)(b * SEQL + SEQL - 1) * DT_ + d];
    size_t o = (size_t)(b * SEQL + i) * DT_ + d;
    float yv = y[o];
    yv = yv / (1.f + __expf(-yv));
    p[o] = hr * yv;
  }
}

extern "C" void kernel_launch(void* const* d_in, const int* in_sizes, int n_in,
                              void* d_out, int out_size, void* d_ws, size_t ws_size,
                              hipStream_t stream) {
  const float* x        = (const float*)d_in[0];
  const float* tok_in_w = (const float*)d_in[1];
  const float* tok_in_b = (const float*)d_in[2];
  const float* ln1_g    = (const float*)d_in[3];
  const float* ln1_b    = (const float*)d_in[4];
  const float* fc_w     = (const float*)d_in[5];
  const float* fc_b     = (const float*)d_in[6];
  const float* tin_w    = (const float*)d_in[7];
  const float* tin_b    = (const float*)d_in[8];
  const float* a_w      = (const float*)d_in[9];
  const float* h0       = (const float*)d_in[10];
  const float* tout_w   = (const float*)d_in[11];
  const float* tout_b   = (const float*)d_in[12];
  const float* ln2_g    = (const float*)d_in[13];
  const float* ln2_b    = (const float*)d_in[14];
  const float* ffn_w1   = (const float*)d_in[15];
  const float* ffn_b1   = (const float*)d_in[16];
  const float* ffn_w2   = (const float*)d_in[17];
  const float* ffn_b2   = (const float*)d_in[18];
  const float* lnf_g    = (const float*)d_in[19];
  const float* lnf_b    = (const float*)d_in[20];
  const float* tok_out_w = (const float*)d_in[21];
  const float* tok_out_b = (const float*)d_in[22];
  float* out = (float*)d_out;

  float* ws = (float*)d_ws;
  float* h  = ws;                 // 1024*512
  float* xn = h + 524288;         // 1024*512
  float* y  = xn + 524288;        // 1024*64   (y,u contiguous for one fill0)
  float* u  = y + 65536;          // 1024*64
  float* za = u + 65536;          // 1024*128
  float* p  = za + 131072;        // 1024*64
  float* f1 = p + 65536;          // 1024*2048
  short* wb = (short*)(f1 + 2097152);  // 32000*512 bf16 = 8192000 float-slots
  const bool use_wbf = ws_size >= (size_t)(3473408 + 8192000) * 4;

  dim3 blk(256);

  // h = x @ tok_in_w.T + tok_in_b. Split-K z=32 (1024 blocks), bias at z==0.
  fill0<<<512, blk, 0, stream>>>(h);
  gemm_bt<128, 128, 0, false, true, true, true><<<dim3(4, 8, 32), blk, 0, stream>>>(
      x, tok_in_w, tok_in_b, nullptr, h, 1024, 512, 32000, 1024);

  for (int l = 0; l < 3; l++) {
    ln512<<<256, blk, 0, stream>>>(h, ln1_g + l * 512, ln1_b + l * 512, xn);
    // y,u zero in one pass (contiguous 131072 floats).
    fill0<<<128, blk, 0, stream>>>(y);
    // fc: y = xn @ fc_w.T + fc_b (pre-act; silu in scan_all). 32x64, z=8.
    gemm_bt<32, 64, 0, false, true, true, true><<<dim3(1, 32, 8), blk, 0, stream>>>(
        xn, fc_w + l * 32768, fc_b + l * 64, nullptr, y, 1024, 64, 512, 64);
    // tin: u = xn @ tin_w.T + tin_b. 32x64, z=8.
    gemm_bt<32, 64, 0, false, true, true, true><<<dim3(1, 32, 8), blk, 0, stream>>>(
        xn, tin_w + l * 32768, tin_b + l * 64, nullptr, u, 1024, 64, 512, 64);
    // za = u @ a_w.T. 32x64 tiles -> 64 blocks.
    gemm_bt<32, 64, 0, false, false, false, true><<<dim3(2, 32, 1), blk, 0, stream>>>(
        u, a_w + l * 8192, nullptr, nullptr, za, 1024, 128, 64, 64);
    scan_all<<<2, 1024, 0, stream>>>(za, u, h0 + l * 128, y, p);
    // tout: h = p @ tout_w.T + tout_b + h. 64x64 tiles -> 128 blocks.
    gemm_bt<64, 64, 0, true, false, true, true><<<dim3(8, 16, 1), blk, 0, stream>>>(
        p, tout_w + l * 32768, tout_b + l * 512, h, h, 1024, 512, 64, 64);
    ln512<<<256, blk, 0, stream>>>(h, ln2_g + l * 512, ln2_b + l * 512, xn);
    // ffn1: f1 = xn @ w1.T + b1 (pre-act). z=4 -> 512 blocks.
    fill0<<<2048, blk, 0, stream>>>(f1);
    gemm_bt<128, 128, 0, false, true, true, true><<<dim3(16, 8, 4), blk, 0, stream>>>(
        xn, ffn_w1 + l * 1048576, ffn_b1 + l * 2048, nullptr, f1, 1024, 2048, 512, 128);
    // ffn2: h += silu(f1) @ w2.T + b2. z=16 -> 512 blocks, silu on A-staging,
    // bias at z==0, residual already in h.
    gemm_bt<128, 128, 0, false, true, true, true, 1><<<dim3(4, 8, 16), blk, 0, stream>>>(
        f1, ffn_w2 + l * 1048576, ffn_b2 + l * 512, nullptr, h, 1024, 512, 2048, 128);
  }

  ln512<<<256, blk, 0, stream>>>(h, lnf_g, lnf_b, xn);
  if (use_wbf) {
    // Pre-convert tok_out_w to bf16 once; vocab GEMM copies W straight to LDS.
    cvt_rne<<<16000, blk, 0, stream>>>(tok_out_w, wb);
    gemm_bt<128, 128, 0, false, false, true, false, 0, true><<<dim3(250, 8, 1), blk, 0, stream>>>(
        xn, (const float*)wb, tok_out_b, nullptr, out, 1024, 32000, 512, 512);
  } else {
    gemm_bt<128, 128, 0, false, false, true, false><<<dim3(250, 8, 1), blk, 0, stream>>>(
        xn, tok_out_w, tok_out_b, nullptr, out, 1024, 32000, 512, 512);
  }
}

// Round 3
// 1113.691 us; speedup vs baseline: 1.0034x; 1.0034x over previous
//
#include <hip/hip_runtime.h>
#include <hip/hip_bf16.h>

// SioConvNet on MI355X. Round 5: XCD swizzle on tok_in + revert mid-GEMM geometry.
//  - tok_in: 1D grid 1024, decode y=b&7,x=(b>>3)&3,z=b>>5 -> b%8=y puts all
//    blocks sharing an A row-panel on ONE XCD (A served from its L2; fetch
//    320MB -> ~200MB compulsory-ish).
//  - Mid GEMMs back to round-1 geometry (64x64 z=4 fc/tin, ffn1 z=2, ffn2 z=8,
//    tout 64x128) -- round-2's smaller-tile/deeper-split versions regressed.
//  - fc+tin merged into one DUAL dispatch (same A; W/bias/C selected by bx).
//  - Kept from round 2: truncation split2, bias-fold@z==0, fused scan, WBF vocab.
// Split-bf16 (hi+lo, 3-pass MFMA) on every GEMM feeding the recurrence
// (za phase sensitivity amplifies bf16-level error ~100x). Vocab GEMM single bf16.
// DEPTH=3, DIM=512, DFF=2048, DT=64, VOCAB=32000, B=2, L=512, M=B*L=1024.

#define LDIM 512
#define SEQL 512
#define DT_ 64
#define NC 16
#define CL 32
#define BK 32

typedef short s16x4 __attribute__((ext_vector_type(4)));
typedef short s16x8 __attribute__((ext_vector_type(8)));
typedef float f32x4 __attribute__((ext_vector_type(4)));

__device__ __forceinline__ unsigned short f2bf(float f) {  // RNE
  unsigned u = __builtin_bit_cast(unsigned, f);
  return (unsigned short)((u + 0x7fffu + ((u >> 16) & 1u)) >> 16);
}

// Truncation split: hi = f with low mantissa zeroed; lo = trunc16(f - hi).
__device__ __forceinline__ void split2(float f, short& hi, short& lo) {
  unsigned u = __builtin_bit_cast(unsigned, f);
  hi = (short)(u >> 16);
  float hf = __builtin_bit_cast(float, u & 0xFFFF0000u);
  float lf = f - hf;  // exact
  lo = (short)(__builtin_bit_cast(unsigned, lf) >> 16);
}

// C[M,N] = act(A[M,K] @ W[N,K]^T + bias) (+R). A, W row-major, K contiguous.
// ACT: 0=none, 1=silu (post-sum). ATOM: atomicAdd into C (split-K); bias applied
// only by z==0. SPL: split-bf16 hi/lo 3-pass MFMA (fp32-class).
// AACT: 1 = silu(A) while staging. WBF: W pre-converted bf16 (shorts).
// SWZ: 1D-grid XCD swizzle for tok_in shape (4 x-tiles, 8 y-tiles): b%8 = y.
// DUAL: blockIdx.x==1 switches to (W2, bias2, C2), n0 stays 0.
template <int BM, int BN, int ACT, bool RES, bool ATOM, bool BIAS, bool SPL,
          int AACT = 0, bool WBF = false, bool SWZ = false, bool DUAL = false>
__global__ __launch_bounds__(256) void gemm_bt(
    const float* __restrict__ A, const float* __restrict__ W,
    const float* __restrict__ bias, const float* __restrict__ R,
    float* __restrict__ C, int M, int N, int K, int kc,
    const float* __restrict__ W2, const float* __restrict__ bias2,
    float* __restrict__ C2) {
  constexpr int WM = BM / 2, WN = BN / 2, TM = WM / 16, TN = WN / 16;
  constexpr int LDA = BK + 8;  // rows 80B apart -> 16B-aligned, 2-way-bank (free)
  constexpr int PLANES = SPL ? 2 : 1;
  __shared__ __align__(16) short As[BM * LDA * PLANES];
  __shared__ __align__(16) short Bs[BN * LDA * PLANES];

  const int tid = threadIdx.x;
  const int wid = tid >> 6, lane = tid & 63;
  const int q = lane >> 4, l16 = lane & 15;
  const int wm = (wid >> 1) * WM, wn = (wid & 1) * WN;

  int bx, by, bz;
  if constexpr (SWZ) {
    int b = blockIdx.x;
    by = b & 7; bx = (b >> 3) & 3; bz = b >> 5;
  } else {
    bx = blockIdx.x; by = blockIdx.y; bz = blockIdx.z;
  }
  if constexpr (DUAL) {
    if (bx) { W = W2; bias = bias2; C = C2; }
    bx = 0;
  }
  const int m0 = by * BM, n0 = bx * BN;
  const int kbeg = bz * kc;
  const int kend = min(K, kbeg + kc);

  f32x4 acc[TM][TN] = {};

  constexpr int AF = BM * BK / 1024;  // float4 loads per thread for A tile
  constexpr int BF = BN * BK / 1024;

  for (int k0 = kbeg; k0 < kend; k0 += BK) {
#pragma unroll
    for (int t = 0; t < AF; t++) {
      int fi = tid + t * 256;
      int row = fi >> 3, col = (fi & 7) << 2;
      float4 v = *(const float4*)(A + (size_t)(m0 + row) * K + k0 + col);
      float* vp = (float*)&v;
      s16x4 hv, lv;
#pragma unroll
      for (int c = 0; c < 4; c++) {
        if (AACT == 1) vp[c] = vp[c] / (1.f + __expf(-vp[c]));
        if (SPL) {
          short h_, l_;
          split2(vp[c], h_, l_);
          hv[c] = h_; lv[c] = l_;
        } else {
          hv[c] = (short)f2bf(vp[c]);
        }
      }
      *(s16x4*)(&As[row * LDA + col]) = hv;
      if (SPL) *(s16x4*)(&As[BM * LDA + row * LDA + col]) = lv;
    }
    if constexpr (WBF) {
      // W already bf16: pure 16B copies, zero conversion VALU.
      const short* Wb = (const short*)W;
      constexpr int BF2 = BN / 64;  // 16B chunks per thread
#pragma unroll
      for (int t = 0; t < BF2; t++) {
        int fi = tid + t * 256;
        int row = fi >> 2, col8 = (fi & 3) << 3;
        s16x8 v = *(const s16x8*)(Wb + (size_t)(n0 + row) * K + k0 + col8);
        *(s16x8*)(&Bs[row * LDA + col8]) = v;
      }
    } else {
#pragma unroll
      for (int t = 0; t < BF; t++) {
        int fi = tid + t * 256;
        int row = fi >> 3, col = (fi & 7) << 2;
        float4 v = *(const float4*)(W + (size_t)(n0 + row) * K + k0 + col);
        const float* vp = (const float*)&v;
        s16x4 hv, lv;
#pragma unroll
        for (int c = 0; c < 4; c++) {
          if (SPL) {
            short h_, l_;
            split2(vp[c], h_, l_);
            hv[c] = h_; lv[c] = l_;
          } else {
            hv[c] = (short)f2bf(vp[c]);
          }
        }
        *(s16x4*)(&Bs[row * LDA + col]) = hv;
        if (SPL) *(s16x4*)(&Bs[BN * LDA + row * LDA + col]) = lv;
      }
    }
    __syncthreads();
    s16x8 ah[TM], bh[TN], al[TM], bl[TN];
#pragma unroll
    for (int i = 0; i < TM; i++) {
      ah[i] = *(const s16x8*)(&As[(wm + i * 16 + l16) * LDA + q * 8]);
      if (SPL) al[i] = *(const s16x8*)(&As[BM * LDA + (wm + i * 16 + l16) * LDA + q * 8]);
    }
#pragma unroll
    for (int j = 0; j < TN; j++) {
      bh[j] = *(const s16x8*)(&Bs[(wn + j * 16 + l16) * LDA + q * 8]);
      if (SPL) bl[j] = *(const s16x8*)(&Bs[BN * LDA + (wn + j * 16 + l16) * LDA + q * 8]);
    }
#pragma unroll
    for (int i = 0; i < TM; i++)
#pragma unroll
      for (int j = 0; j < TN; j++) {
        acc[i][j] = __builtin_amdgcn_mfma_f32_16x16x32_bf16(ah[i], bh[j], acc[i][j], 0, 0, 0);
        if (SPL) {
          acc[i][j] = __builtin_amdgcn_mfma_f32_16x16x32_bf16(ah[i], bl[j], acc[i][j], 0, 0, 0);
          acc[i][j] = __builtin_amdgcn_mfma_f32_16x16x32_bf16(al[i], bh[j], acc[i][j], 0, 0, 0);
        }
      }
    __syncthreads();
  }

#pragma unroll
  for (int i = 0; i < TM; i++)
#pragma unroll
    for (int j = 0; j < TN; j++)
#pragma unroll
      for (int r = 0; r < 4; r++) {
        int m = m0 + wm + i * 16 + q * 4 + r;
        int n = n0 + wn + j * 16 + l16;
        float v = acc[i][j][r];
        if (BIAS && kbeg == 0) v += bias[n];
        if (ACT == 1) v = v / (1.f + __expf(-v));
        if (RES) v += R[(size_t)m * N + n];
        if (ATOM) atomicAdd(&C[(size_t)m * N + n], v);
        else C[(size_t)m * N + n] = v;
      }
}

// Zero-fill (count divisible by 1024).
__global__ __launch_bounds__(256) void fill0(float* __restrict__ p) {
  size_t i = (size_t)(blockIdx.x * 256 + threadIdx.x) * 4;
  *(float4*)(p + i) = make_float4(0.f, 0.f, 0.f, 0.f);
}

// fp32 -> bf16 (RNE) streaming convert, 4 elems/thread.
__global__ __launch_bounds__(256) void cvt_rne(const float* __restrict__ src,
                                               short* __restrict__ dst) {
  size_t i = (size_t)(blockIdx.x * 256 + threadIdx.x) * 4;
  float4 v = *(const float4*)(src + i);
  const float* vp = (const float*)&v;
  s16x4 o;
#pragma unroll
  for (int c = 0; c < 4; c++) o[c] = (short)f2bf(vp[c]);
  *(s16x4*)(dst + i) = o;
}

// LayerNorm over last dim 512; one wave per row.
__global__ __launch_bounds__(256) void ln512(const float* __restrict__ x,
                                             const float* __restrict__ g,
                                             const float* __restrict__ b,
                                             float* __restrict__ o) {
  int wid = threadIdx.x >> 6, lane = threadIdx.x & 63;
  int row = blockIdx.x * 4 + wid;
  const float* xr = x + (size_t)row * 512 + lane * 8;
  float4 v0 = *(const float4*)xr;
  float4 v1 = *(const float4*)(xr + 4);
  float s = v0.x + v0.y + v0.z + v0.w + v1.x + v1.y + v1.z + v1.w;
  float ss = v0.x * v0.x + v0.y * v0.y + v0.z * v0.z + v0.w * v0.w +
             v1.x * v1.x + v1.y * v1.y + v1.z * v1.z + v1.w * v1.w;
#pragma unroll
  for (int m = 32; m; m >>= 1) { s += __shfl_xor(s, m); ss += __shfl_xor(ss, m); }
  float mean = s * (1.f / 512.f);
  float var = ss * (1.f / 512.f) - mean * mean;
  float rstd = rsqrtf(var + 1e-5f);
  const float* gp = g + lane * 8;
  const float* bp = b + lane * 8;
  float4 g0 = *(const float4*)gp, g1 = *(const float4*)(gp + 4);
  float4 b0 = *(const float4*)bp, b1 = *(const float4*)(bp + 4);
  float* op = o + (size_t)row * 512 + lane * 8;
  float4 r0, r1;
  r0.x = (v0.x - mean) * rstd * g0.x + b0.x;
  r0.y = (v0.y - mean) * rstd * g0.y + b0.y;
  r0.z = (v0.z - mean) * rstd * g0.z + b0.z;
  r0.w = (v0.w - mean) * rstd * g0.w + b0.w;
  r1.x = (v1.x - mean) * rstd * g1.x + b1.x;
  r1.y = (v1.y - mean) * rstd * g1.y + b1.y;
  r1.z = (v1.z - mean) * rstd * g1.z + b1.z;
  r1.w = (v1.w - mean) * rstd * g1.w + b1.w;
  *(float4*)op = r0;
  *(float4*)(op + 4) = r1;
}

// a[b,i,d] from za: a = za * rsqrt(|za|^2) * exp(-|za|^2)
__device__ __forceinline__ float2 a_of(const float* __restrict__ za, int b, int i, int d) {
  float zr = za[(size_t)(b * SEQL + i) * 128 + 2 * d];
  float zi = za[(size_t)(b * SEQL + i) * 128 + 2 * d + 1];
  float m2 = zr * zr + zi * zi;
  float sc = rsqrtf(m2) * __expf(-m2);
  return make_float2(zr * sc, zi * sc);
}

// xsm1[i]: 0 for i==0, h0c for i==1, u[i-2] (real) otherwise.
__device__ __forceinline__ float2 xsm1_of(const float* __restrict__ u,
                                          const float* __restrict__ h0,
                                          int b, int i, int d) {
  if (i == 0) return make_float2(0.f, 0.f);
  if (i == 1) return make_float2(h0[d * 2], h0[d * 2 + 1]);
  return make_float2(u[(size_t)(b * SEQL + i - 2) * DT_ + d], 0.f);
}

// Fused backward chunked scan (p1+p2+p3). One block per batch element b;
// 1024 threads = (chunk c = t>>6) x (d = t&63). p = real(h) * silu(y).
__global__ __launch_bounds__(1024) void scan_all(const float* __restrict__ za,
                                                 const float* __restrict__ u,
                                                 const float* __restrict__ h0,
                                                 const float* __restrict__ y,
                                                 float* __restrict__ p) {
  __shared__ float2 sA[NC * 64], sB[NC * 64], sT[NC * 64];
  const int b = blockIdx.x;
  const int t = threadIdx.x;
  const int d = t & 63, c = t >> 6;  // c in [0,16)

  // Phase 1: per-chunk (A = prod a, Bv = backward eval with t_end = 0).
  float2 Aa = make_float2(1.f, 0.f), Bv = make_float2(0.f, 0.f);
  for (int i = c * CL + CL - 1; i >= c * CL; i--) {
    float2 a = a_of(za, b, i, d);
    float2 xs = xsm1_of(u, h0, b, i, d);
    float2 nb, nA;
    nb.x = xs.x + a.x * Bv.x - a.y * Bv.y;
    nb.y = xs.y + a.x * Bv.y + a.y * Bv.x;
    nA.x = a.x * Aa.x - a.y * Aa.y;
    nA.y = a.x * Aa.y + a.y * Aa.x;
    Bv = nb; Aa = nA;
  }
  sA[c * 64 + d] = Aa;
  sB[c * 64 + d] = Bv;
  __syncthreads();

  // Phase 2: serial backward combine over the NC chunks (64 threads active).
  if (c == 0) {
    float2 tt = make_float2(u[(size_t)(b * SEQL + SEQL - 2) * DT_ + d], 0.f);
    for (int cc = NC - 1; cc >= 0; cc--) {
      sT[cc * 64 + d] = tt;
      float2 A = sA[cc * 64 + d], Bc = sB[cc * 64 + d];
      float2 nt;
      nt.x = A.x * tt.x - A.y * tt.y + Bc.x;
      nt.y = A.x * tt.y + A.y * tt.x + Bc.y;
      tt = nt;
    }
  }
  __syncthreads();

  // Phase 3: redo chunk backward scan from known t_end; write p.
  float2 tt = sT[c * 64 + d];
  for (int i = c * CL + CL - 1; i >= c * CL; i--) {
    float2 a = a_of(za, b, i, d);
    float2 xs = xsm1_of(u, h0, b, i, d);
    float2 nt;
    nt.x = xs.x + a.x * tt.x - a.y * tt.y;
    nt.y = xs.y + a.x * tt.y + a.y * tt.x;
    tt = nt;
    float hr = tt.x;
    if (i == SEQL - 1) hr += u[(size_t)(b * SEQL + SEQL - 1) * DT_ + d];
    size_t o = (size_t)(b * SEQL + i) * DT_ + d;
    float yv = y[o];
    yv = yv / (1.f + __expf(-yv));
    p[o] = hr * yv;
  }
}

extern "C" void kernel_launch(void* const* d_in, const int* in_sizes, int n_in,
                              void* d_out, int out_size, void* d_ws, size_t ws_size,
                              hipStream_t stream) {
  const float* x        = (const float*)d_in[0];
  const float* tok_in_w = (const float*)d_in[1];
  const float* tok_in_b = (const float*)d_in[2];
  const float* ln1_g    = (const float*)d_in[3];
  const float* ln1_b    = (const float*)d_in[4];
  const float* fc_w     = (const float*)d_in[5];
  const float* fc_b     = (const float*)d_in[6];
  const float* tin_w    = (const float*)d_in[7];
  const float* tin_b    = (const float*)d_in[8];
  const float* a_w      = (const float*)d_in[9];
  const float* h0       = (const float*)d_in[10];
  const float* tout_w   = (const float*)d_in[11];
  const float* tout_b   = (const float*)d_in[12];
  const float* ln2_g    = (const float*)d_in[13];
  const float* ln2_b    = (const float*)d_in[14];
  const float* ffn_w1   = (const float*)d_in[15];
  const float* ffn_b1   = (const float*)d_in[16];
  const float* ffn_w2   = (const float*)d_in[17];
  const float* ffn_b2   = (const float*)d_in[18];
  const float* lnf_g    = (const float*)d_in[19];
  const float* lnf_b    = (const float*)d_in[20];
  const float* tok_out_w = (const float*)d_in[21];
  const float* tok_out_b = (const float*)d_in[22];
  float* out = (float*)d_out;

  float* ws = (float*)d_ws;
  float* h  = ws;                 // 1024*512
  float* xn = h + 524288;         // 1024*512
  float* y  = xn + 524288;        // 1024*64   (y,u contiguous: one fill0)
  float* u  = y + 65536;          // 1024*64
  float* za = u + 65536;          // 1024*128
  float* p  = za + 131072;        // 1024*64
  float* f1 = p + 65536;          // 1024*2048
  short* wb = (short*)(f1 + 2097152);  // 32000*512 bf16 = 8192000 float-slots
  const bool use_wbf = ws_size >= (size_t)(3473408 + 8192000) * 4;

  dim3 blk(256);

  // h = x @ tok_in_w.T + tok_in_b. Split-K z=32, XCD-swizzled 1D grid:
  // b%8 = y-tile -> all 128 blocks sharing an A row-panel co-resident on one
  // XCD (A via its L2). Bias at z==0.
  fill0<<<512, blk, 0, stream>>>(h);
  gemm_bt<128, 128, 0, false, true, true, true, 0, false, true>
      <<<dim3(1024), blk, 0, stream>>>(
      x, tok_in_w, tok_in_b, nullptr, h, 1024, 512, 32000, 1024,
      nullptr, nullptr, nullptr);

  for (int l = 0; l < 3; l++) {
    ln512<<<256, blk, 0, stream>>>(h, ln1_g + l * 512, ln1_b + l * 512, xn);
    // y,u zero in one pass (contiguous 131072 floats).
    fill0<<<128, blk, 0, stream>>>(y);
    // fc+tin merged: bx=0 -> y=xn@fc_w.T+fc_b (pre-act, silu in scan_all);
    // bx=1 -> u=xn@tin_w.T+tin_b. 64x64 tiles, z=4 -> 128 blocks.
    gemm_bt<64, 64, 0, false, true, true, true, 0, false, false, true>
        <<<dim3(2, 16, 4), blk, 0, stream>>>(
        xn, fc_w + l * 32768, fc_b + l * 64, nullptr, y, 1024, 64, 512, 128,
        tin_w + l * 32768, tin_b + l * 64, u);
    // za = u @ a_w.T. 64x64 tiles -> 32 blocks.
    gemm_bt<64, 64, 0, false, false, false, true><<<dim3(2, 16, 1), blk, 0, stream>>>(
        u, a_w + l * 8192, nullptr, nullptr, za, 1024, 128, 64, 64,
        nullptr, nullptr, nullptr);
    scan_all<<<2, 1024, 0, stream>>>(za, u, h0 + l * 128, y, p);
    // tout: h = p @ tout_w.T + tout_b + h. 64x128 tiles -> 64 blocks.
    gemm_bt<64, 128, 0, true, false, true, true><<<dim3(4, 16, 1), blk, 0, stream>>>(
        p, tout_w + l * 32768, tout_b + l * 512, h, h, 1024, 512, 64, 64,
        nullptr, nullptr, nullptr);
    ln512<<<256, blk, 0, stream>>>(h, ln2_g + l * 512, ln2_b + l * 512, xn);
    // ffn1: f1 = xn @ w1.T + b1 (pre-act). z=2 -> 256 blocks.
    fill0<<<2048, blk, 0, stream>>>(f1);
    gemm_bt<128, 128, 0, false, true, true, true><<<dim3(16, 8, 2), blk, 0, stream>>>(
        xn, ffn_w1 + l * 1048576, ffn_b1 + l * 2048, nullptr, f1, 1024, 2048, 512, 256,
        nullptr, nullptr, nullptr);
    // ffn2: h += silu(f1) @ w2.T + b2. z=8 -> 256 blocks, silu on A-staging,
    // bias at z==0, residual already in h.
    gemm_bt<128, 128, 0, false, true, true, true, 1><<<dim3(4, 8, 8), blk, 0, stream>>>(
        f1, ffn_w2 + l * 1048576, ffn_b2 + l * 512, nullptr, h, 1024, 512, 2048, 256,
        nullptr, nullptr, nullptr);
  }

  ln512<<<256, blk, 0, stream>>>(h, lnf_g, lnf_b, xn);
  if (use_wbf) {
    // Pre-convert tok_out_w to bf16 once; vocab GEMM copies W straight to LDS.
    cvt_rne<<<16000, blk, 0, stream>>>(tok_out_w, wb);
    gemm_bt<128, 128, 0, false, false, true, false, 0, true>
        <<<dim3(250, 8, 1), blk, 0, stream>>>(
        xn, (const float*)wb, tok_out_b, nullptr, out, 1024, 32000, 512, 512,
        nullptr, nullptr, nullptr);
  } else {
    gemm_bt<128, 128, 0, false, false, true, false><<<dim3(250, 8, 1), blk, 0, stream>>>(
        xn, tok_out_w, tok_out_b, nullptr, out, 1024, 32000, 512, 512,
        nullptr, nullptr, nullptr);
  }
}

// Round 4
// 1065.434 us; speedup vs baseline: 1.0489x; 1.0453x over previous
//
#include <hip/hip_runtime.h>
#include <hip/hip_bf16.h>

// SioConvNet on MI355X. Round 6: register-prefetch pipeline in gemm_bt.
//  - Per K-step: store regs->LDS, sync, ISSUE next tile's global loads (into
//    regs), then fragment-reads + MFMA run while loads fly (T14 issue-early/
//    write-late). Hides ~900cyc HBM latency under ~400cyc of compute at the
//    measured ~2-3 waves/SIMD. Applies to every GEMM dispatch.
//  - Scan un-fused back to known-good 8-block p1/p2/p3 (round-2 fusion to 2
//    blocks was the likely ~30-60us remainder regression; silu stays in p3).
//  - SWZ removed (round-3 null: A row-panel 16.4MB >> 4MiB XCD L2).
//  - Kept: truncation split2, bias-fold@z==0, DUAL fc/tin, WBF vocab.
// Split-bf16 (hi+lo, 3-pass MFMA) on every GEMM feeding the recurrence
// (za phase sensitivity amplifies bf16-level error ~100x). Vocab GEMM single bf16.
// DEPTH=3, DIM=512, DFF=2048, DT=64, VOCAB=32000, B=2, L=512, M=B*L=1024.

#define LDIM 512
#define SEQL 512
#define DT_ 64
#define NC 16
#define CL 32
#define BK 32

typedef short s16x4 __attribute__((ext_vector_type(4)));
typedef short s16x8 __attribute__((ext_vector_type(8)));
typedef float f32x4 __attribute__((ext_vector_type(4)));

__device__ __forceinline__ unsigned short f2bf(float f) {  // RNE
  unsigned u = __builtin_bit_cast(unsigned, f);
  return (unsigned short)((u + 0x7fffu + ((u >> 16) & 1u)) >> 16);
}

// Truncation split: hi = f with low mantissa zeroed; lo = trunc16(f - hi).
__device__ __forceinline__ void split2(float f, short& hi, short& lo) {
  unsigned u = __builtin_bit_cast(unsigned, f);
  hi = (short)(u >> 16);
  float hf = __builtin_bit_cast(float, u & 0xFFFF0000u);
  float lf = f - hf;  // exact
  lo = (short)(__builtin_bit_cast(unsigned, lf) >> 16);
}

// C[M,N] = act(A[M,K] @ W[N,K]^T + bias) (+R). A, W row-major, K contiguous.
// ACT: 0=none, 1=silu (post-sum). ATOM: atomicAdd into C (split-K); bias applied
// only by z==0. SPL: split-bf16 hi/lo 3-pass MFMA (fp32-class).
// AACT: 1 = silu(A) while staging. WBF: W pre-converted bf16 (shorts).
// DUAL: blockIdx.x==1 switches to (W2, bias2, C2), n0 stays 0.
template <int BM, int BN, int ACT, bool RES, bool ATOM, bool BIAS, bool SPL,
          int AACT = 0, bool WBF = false, bool DUAL = false>
__global__ __launch_bounds__(256) void gemm_bt(
    const float* __restrict__ A, const float* __restrict__ W,
    const float* __restrict__ bias, const float* __restrict__ R,
    float* __restrict__ C, int M, int N, int K, int kc,
    const float* __restrict__ W2, const float* __restrict__ bias2,
    float* __restrict__ C2) {
  constexpr int WM = BM / 2, WN = BN / 2, TM = WM / 16, TN = WN / 16;
  constexpr int LDA = BK + 8;  // rows 80B apart -> 16B-aligned, 2-way-bank (free)
  constexpr int PLANES = SPL ? 2 : 1;
  __shared__ __align__(16) short As[BM * LDA * PLANES];
  __shared__ __align__(16) short Bs[BN * LDA * PLANES];

  const int tid = threadIdx.x;
  const int wid = tid >> 6, lane = tid & 63;
  const int q = lane >> 4, l16 = lane & 15;
  const int wm = (wid >> 1) * WM, wn = (wid & 1) * WN;

  int bx = blockIdx.x, by = blockIdx.y, bz = blockIdx.z;
  if constexpr (DUAL) {
    if (bx) { W = W2; bias = bias2; C = C2; }
    bx = 0;
  }
  const int m0 = by * BM, n0 = bx * BN;
  const int kbeg = bz * kc;
  const int kend = min(K, kbeg + kc);

  f32x4 acc[TM][TN] = {};

  constexpr int AF = BM * BK / 1024;  // float4 loads per thread for A tile
  constexpr int BF = BN * BK / 1024;
  constexpr int WF = WBF ? (BN / 64) : 1;  // s16x8 loads per thread (WBF)

  float4 pa[AF];
  float4 pb[WBF ? 1 : BF];
  s16x8 pw[WF];

  auto load_a = [&](int k0) {
#pragma unroll
    for (int t = 0; t < AF; t++) {
      int fi = tid + t * 256;
      int row = fi >> 3, col = (fi & 7) << 2;
      pa[t] = *(const float4*)(A + (size_t)(m0 + row) * K + k0 + col);
    }
  };
  auto load_b = [&](int k0) {
    if constexpr (WBF) {
      const short* Wb = (const short*)W;
#pragma unroll
      for (int t = 0; t < WF; t++) {
        int fi = tid + t * 256;
        int row = fi >> 2, col8 = (fi & 3) << 3;
        pw[t] = *(const s16x8*)(Wb + (size_t)(n0 + row) * K + k0 + col8);
      }
    } else {
#pragma unroll
      for (int t = 0; t < BF; t++) {
        int fi = tid + t * 256;
        int row = fi >> 3, col = (fi & 7) << 2;
        pb[t] = *(const float4*)(W + (size_t)(n0 + row) * K + k0 + col);
      }
    }
  };
  auto store_tiles = [&]() {
#pragma unroll
    for (int t = 0; t < AF; t++) {
      int fi = tid + t * 256;
      int row = fi >> 3, col = (fi & 7) << 2;
      float4 v = pa[t];
      float* vp = (float*)&v;
      s16x4 hv, lv;
#pragma unroll
      for (int c = 0; c < 4; c++) {
        if (AACT == 1) vp[c] = vp[c] / (1.f + __expf(-vp[c]));
        if (SPL) {
          short h_, l_;
          split2(vp[c], h_, l_);
          hv[c] = h_; lv[c] = l_;
        } else {
          hv[c] = (short)f2bf(vp[c]);
        }
      }
      *(s16x4*)(&As[row * LDA + col]) = hv;
      if (SPL) *(s16x4*)(&As[BM * LDA + row * LDA + col]) = lv;
    }
    if constexpr (WBF) {
#pragma unroll
      for (int t = 0; t < WF; t++) {
        int fi = tid + t * 256;
        int row = fi >> 2, col8 = (fi & 3) << 3;
        *(s16x8*)(&Bs[row * LDA + col8]) = pw[t];
      }
    } else {
#pragma unroll
      for (int t = 0; t < BF; t++) {
        int fi = tid + t * 256;
        int row = fi >> 3, col = (fi & 7) << 2;
        float4 v = pb[t];
        const float* vp = (const float*)&v;
        s16x4 hv, lv;
#pragma unroll
        for (int c = 0; c < 4; c++) {
          if (SPL) {
            short h_, l_;
            split2(vp[c], h_, l_);
            hv[c] = h_; lv[c] = l_;
          } else {
            hv[c] = (short)f2bf(vp[c]);
          }
        }
        *(s16x4*)(&Bs[row * LDA + col]) = hv;
        if (SPL) *(s16x4*)(&Bs[BN * LDA + row * LDA + col]) = lv;
      }
    }
  };

  load_a(kbeg);
  load_b(kbeg);
  for (int k0 = kbeg; k0 < kend; k0 += BK) {
    store_tiles();
    __syncthreads();
    if (k0 + BK < kend) {  // issue next tile's loads; they fly under the MFMAs
      load_a(k0 + BK);
      load_b(k0 + BK);
    }
    s16x8 ah[TM], bh[TN], al[TM], bl[TN];
#pragma unroll
    for (int i = 0; i < TM; i++) {
      ah[i] = *(const s16x8*)(&As[(wm + i * 16 + l16) * LDA + q * 8]);
      if (SPL) al[i] = *(const s16x8*)(&As[BM * LDA + (wm + i * 16 + l16) * LDA + q * 8]);
    }
#pragma unroll
    for (int j = 0; j < TN; j++) {
      bh[j] = *(const s16x8*)(&Bs[(wn + j * 16 + l16) * LDA + q * 8]);
      if (SPL) bl[j] = *(const s16x8*)(&Bs[BN * LDA + (wn + j * 16 + l16) * LDA + q * 8]);
    }
#pragma unroll
    for (int i = 0; i < TM; i++)
#pragma unroll
      for (int j = 0; j < TN; j++) {
        acc[i][j] = __builtin_amdgcn_mfma_f32_16x16x32_bf16(ah[i], bh[j], acc[i][j], 0, 0, 0);
        if (SPL) {
          acc[i][j] = __builtin_amdgcn_mfma_f32_16x16x32_bf16(ah[i], bl[j], acc[i][j], 0, 0, 0);
          acc[i][j] = __builtin_amdgcn_mfma_f32_16x16x32_bf16(al[i], bh[j], acc[i][j], 0, 0, 0);
        }
      }
    __syncthreads();
  }

#pragma unroll
  for (int i = 0; i < TM; i++)
#pragma unroll
    for (int j = 0; j < TN; j++)
#pragma unroll
      for (int r = 0; r < 4; r++) {
        int m = m0 + wm + i * 16 + q * 4 + r;
        int n = n0 + wn + j * 16 + l16;
        float v = acc[i][j][r];
        if (BIAS && kbeg == 0) v += bias[n];
        if (ACT == 1) v = v / (1.f + __expf(-v));
        if (RES) v += R[(size_t)m * N + n];
        if (ATOM) atomicAdd(&C[(size_t)m * N + n], v);
        else C[(size_t)m * N + n] = v;
      }
}

// Zero-fill (count divisible by 1024).
__global__ __launch_bounds__(256) void fill0(float* __restrict__ p) {
  size_t i = (size_t)(blockIdx.x * 256 + threadIdx.x) * 4;
  *(float4*)(p + i) = make_float4(0.f, 0.f, 0.f, 0.f);
}

// fp32 -> bf16 (RNE) streaming convert, 4 elems/thread.
__global__ __launch_bounds__(256) void cvt_rne(const float* __restrict__ src,
                                               short* __restrict__ dst) {
  size_t i = (size_t)(blockIdx.x * 256 + threadIdx.x) * 4;
  float4 v = *(const float4*)(src + i);
  const float* vp = (const float*)&v;
  s16x4 o;
#pragma unroll
  for (int c = 0; c < 4; c++) o[c] = (short)f2bf(vp[c]);
  *(s16x4*)(dst + i) = o;
}

// LayerNorm over last dim 512; one wave per row.
__global__ __launch_bounds__(256) void ln512(const float* __restrict__ x,
                                             const float* __restrict__ g,
                                             const float* __restrict__ b,
                                             float* __restrict__ o) {
  int wid = threadIdx.x >> 6, lane = threadIdx.x & 63;
  int row = blockIdx.x * 4 + wid;
  const float* xr = x + (size_t)row * 512 + lane * 8;
  float4 v0 = *(const float4*)xr;
  float4 v1 = *(const float4*)(xr + 4);
  float s = v0.x + v0.y + v0.z + v0.w + v1.x + v1.y + v1.z + v1.w;
  float ss = v0.x * v0.x + v0.y * v0.y + v0.z * v0.z + v0.w * v0.w +
             v1.x * v1.x + v1.y * v1.y + v1.z * v1.z + v1.w * v1.w;
#pragma unroll
  for (int m = 32; m; m >>= 1) { s += __shfl_xor(s, m); ss += __shfl_xor(ss, m); }
  float mean = s * (1.f / 512.f);
  float var = ss * (1.f / 512.f) - mean * mean;
  float rstd = rsqrtf(var + 1e-5f);
  const float* gp = g + lane * 8;
  const float* bp = b + lane * 8;
  float4 g0 = *(const float4*)gp, g1 = *(const float4*)(gp + 4);
  float4 b0 = *(const float4*)bp, b1 = *(const float4*)(bp + 4);
  float* op = o + (size_t)row * 512 + lane * 8;
  float4 r0, r1;
  r0.x = (v0.x - mean) * rstd * g0.x + b0.x;
  r0.y = (v0.y - mean) * rstd * g0.y + b0.y;
  r0.z = (v0.z - mean) * rstd * g0.z + b0.z;
  r0.w = (v0.w - mean) * rstd * g0.w + b0.w;
  r1.x = (v1.x - mean) * rstd * g1.x + b1.x;
  r1.y = (v1.y - mean) * rstd * g1.y + b1.y;
  r1.z = (v1.z - mean) * rstd * g1.z + b1.z;
  r1.w = (v1.w - mean) * rstd * g1.w + b1.w;
  *(float4*)op = r0;
  *(float4*)(op + 4) = r1;
}

// a[b,i,d] from za: a = za * rsqrt(|za|^2) * exp(-|za|^2)
__device__ __forceinline__ float2 a_of(const float* __restrict__ za, int b, int i, int d) {
  float zr = za[(size_t)(b * SEQL + i) * 128 + 2 * d];
  float zi = za[(size_t)(b * SEQL + i) * 128 + 2 * d + 1];
  float m2 = zr * zr + zi * zi;
  float sc = rsqrtf(m2) * __expf(-m2);
  return make_float2(zr * sc, zi * sc);
}

// xsm1[i]: 0 for i==0, h0c for i==1, u[i-2] (real) otherwise.
__device__ __forceinline__ float2 xsm1_of(const float* __restrict__ u,
                                          const float* __restrict__ h0,
                                          int b, int i, int d) {
  if (i == 0) return make_float2(0.f, 0.f);
  if (i == 1) return make_float2(h0[d * 2], h0[d * 2 + 1]);
  return make_float2(u[(size_t)(b * SEQL + i - 2) * DT_ + d], 0.f);
}

// Phase 1: per (b,d,chunk): A = prod a[i], Bv = backward eval with t_end=0.
__global__ __launch_bounds__(256) void scan_p1(const float* __restrict__ za,
                                               const float* __restrict__ u,
                                               const float* __restrict__ h0,
                                               float2* __restrict__ cA,
                                               float2* __restrict__ cB) {
  int tid = blockIdx.x * 256 + threadIdx.x;  // 2048 = B*NC*D, d fastest
  int d = tid & 63, c = (tid >> 6) & (NC - 1), b = tid >> 10;
  float2 Aa = make_float2(1.f, 0.f), Bv = make_float2(0.f, 0.f);
  for (int i = c * CL + CL - 1; i >= c * CL; i--) {
    float2 a = a_of(za, b, i, d);
    float2 xs = xsm1_of(u, h0, b, i, d);
    float2 nb, nA;
    nb.x = xs.x + a.x * Bv.x - a.y * Bv.y;
    nb.y = xs.y + a.x * Bv.y + a.y * Bv.x;
    nA.x = a.x * Aa.x - a.y * Aa.y;
    nA.y = a.x * Aa.y + a.y * Aa.x;
    Bv = nb; Aa = nA;
  }
  cA[tid] = Aa;
  cB[tid] = Bv;
}

// Phase 2: backward combine over the NC chunks, store t at each chunk end.
__global__ __launch_bounds__(128) void scan_p2(const float* __restrict__ u,
                                               const float2* __restrict__ cA,
                                               const float2* __restrict__ cB,
                                               float2* __restrict__ tE) {
  int tid = threadIdx.x;  // 128 = B*D
  int d = tid & 63, b = tid >> 6;
  float2 t = make_float2(u[(size_t)(b * SEQL + SEQL - 2) * DT_ + d], 0.f);  // t[L]=xs[L-1]
  for (int c = NC - 1; c >= 0; c--) {
    int idx = (b << 10) + (c << 6) + d;
    tE[idx] = t;
    float2 A = cA[idx], Bv = cB[idx];
    float2 nt;
    nt.x = A.x * t.x - A.y * t.y + Bv.x;
    nt.y = A.x * t.y + A.y * t.x + Bv.y;
    t = nt;
  }
}

// Phase 3: redo chunk backward scan from known t_end; p = real(h) * silu(y).
// (y arrives PRE-activation.)
__global__ __launch_bounds__(256) void scan_p3(const float* __restrict__ za,
                                               const float* __restrict__ u,
                                               const float* __restrict__ h0,
                                               const float* __restrict__ y,
                                               const float2* __restrict__ tE,
                                               float* __restrict__ p) {
  int tid = blockIdx.x * 256 + threadIdx.x;
  int d = tid & 63, c = (tid >> 6) & (NC - 1), b = tid >> 10;
  float2 t = tE[tid];
  for (int i = c * CL + CL - 1; i >= c * CL; i--) {
    float2 a = a_of(za, b, i, d);
    float2 xs = xsm1_of(u, h0, b, i, d);
    float2 nt;
    nt.x = xs.x + a.x * t.x - a.y * t.y;
    nt.y = xs.y + a.x * t.y + a.y * t.x;
    t = nt;
    float hr = t.x;
    if (i == SEQL - 1) hr += u[(size_t)(b * SEQL + SEQL - 1) * DT_ + d];
    size_t o = (size_t)(b * SEQL + i) * DT_ + d;
    float yv = y[o];
    yv = yv / (1.f + __expf(-yv));
    p[o] = hr * yv;
  }
}

extern "C" void kernel_launch(void* const* d_in, const int* in_sizes, int n_in,
                              void* d_out, int out_size, void* d_ws, size_t ws_size,
                              hipStream_t stream) {
  const float* x        = (const float*)d_in[0];
  const float* tok_in_w = (const float*)d_in[1];
  const float* tok_in_b = (const float*)d_in[2];
  const float* ln1_g    = (const float*)d_in[3];
  const float* ln1_b    = (const float*)d_in[4];
  const float* fc_w     = (const float*)d_in[5];
  const float* fc_b     = (const float*)d_in[6];
  const float* tin_w    = (const float*)d_in[7];
  const float* tin_b    = (const float*)d_in[8];
  const float* a_w      = (const float*)d_in[9];
  const float* h0       = (const float*)d_in[10];
  const float* tout_w   = (const float*)d_in[11];
  const float* tout_b   = (const float*)d_in[12];
  const float* ln2_g    = (const float*)d_in[13];
  const float* ln2_b    = (const float*)d_in[14];
  const float* ffn_w1   = (const float*)d_in[15];
  const float* ffn_b1   = (const float*)d_in[16];
  const float* ffn_w2   = (const float*)d_in[17];
  const float* ffn_b2   = (const float*)d_in[18];
  const float* lnf_g    = (const float*)d_in[19];
  const float* lnf_b    = (const float*)d_in[20];
  const float* tok_out_w = (const float*)d_in[21];
  const float* tok_out_b = (const float*)d_in[22];
  float* out = (float*)d_out;

  float* ws = (float*)d_ws;
  float* h  = ws;                 // 1024*512
  float* xn = h + 524288;         // 1024*512
  float* y  = xn + 524288;        // 1024*64   (y,u contiguous: one fill0)
  float* u  = y + 65536;          // 1024*64
  float* za = u + 65536;          // 1024*128
  float* p  = za + 131072;        // 1024*64
  float* f1 = p + 65536;          // 1024*2048
  float2* cA = (float2*)(f1 + 2097152);  // 2048
  float2* cB = cA + 2048;
  float2* tE = cB + 2048;
  short* wb = (short*)(tE + 2048);  // 32000*512 bf16 = 8192000 float-slots
  const bool use_wbf = ws_size >= (size_t)(3485696 + 8192000) * 4;

  dim3 blk(256);

  // h = x @ tok_in_w.T + tok_in_b. Split-K z=32 (1024 blocks), bias at z==0.
  fill0<<<512, blk, 0, stream>>>(h);
  gemm_bt<128, 128, 0, false, true, true, true><<<dim3(4, 8, 32), blk, 0, stream>>>(
      x, tok_in_w, tok_in_b, nullptr, h, 1024, 512, 32000, 1024,
      nullptr, nullptr, nullptr);

  for (int l = 0; l < 3; l++) {
    ln512<<<256, blk, 0, stream>>>(h, ln1_g + l * 512, ln1_b + l * 512, xn);
    // y,u zero in one pass (contiguous 131072 floats).
    fill0<<<128, blk, 0, stream>>>(y);
    // fc+tin merged: bx=0 -> y=xn@fc_w.T+fc_b (pre-act, silu in scan_p3);
    // bx=1 -> u=xn@tin_w.T+tin_b. 64x64 tiles, z=4 -> 128 blocks.
    gemm_bt<64, 64, 0, false, true, true, true, 0, false, true>
        <<<dim3(2, 16, 4), blk, 0, stream>>>(
        xn, fc_w + l * 32768, fc_b + l * 64, nullptr, y, 1024, 64, 512, 128,
        tin_w + l * 32768, tin_b + l * 64, u);
    // za = u @ a_w.T. 64x64 tiles -> 32 blocks.
    gemm_bt<64, 64, 0, false, false, false, true><<<dim3(2, 16, 1), blk, 0, stream>>>(
        u, a_w + l * 8192, nullptr, nullptr, za, 1024, 128, 64, 64,
        nullptr, nullptr, nullptr);
    scan_p1<<<8, blk, 0, stream>>>(za, u, h0 + l * 128, cA, cB);
    scan_p2<<<1, 128, 0, stream>>>(u, cA, cB, tE);
    scan_p3<<<8, blk, 0, stream>>>(za, u, h0 + l * 128, y, tE, p);
    // tout: h = p @ tout_w.T + tout_b + h. 64x128 tiles -> 64 blocks.
    gemm_bt<64, 128, 0, true, false, true, true><<<dim3(4, 16, 1), blk, 0, stream>>>(
        p, tout_w + l * 32768, tout_b + l * 512, h, h, 1024, 512, 64, 64,
        nullptr, nullptr, nullptr);
    ln512<<<256, blk, 0, stream>>>(h, ln2_g + l * 512, ln2_b + l * 512, xn);
    // ffn1: f1 = xn @ w1.T + b1 (pre-act). z=2 -> 256 blocks.
    fill0<<<2048, blk, 0, stream>>>(f1);
    gemm_bt<128, 128, 0, false, true, true, true><<<dim3(16, 8, 2), blk, 0, stream>>>(
        xn, ffn_w1 + l * 1048576, ffn_b1 + l * 2048, nullptr, f1, 1024, 2048, 512, 256,
        nullptr, nullptr, nullptr);
    // ffn2: h += silu(f1) @ w2.T + b2. z=8 -> 256 blocks, silu on A-staging,
    // bias at z==0, residual already in h.
    gemm_bt<128, 128, 0, false, true, true, true, 1><<<dim3(4, 8, 8), blk, 0, stream>>>(
        f1, ffn_w2 + l * 1048576, ffn_b2 + l * 512, nullptr, h, 1024, 512, 2048, 256,
        nullptr, nullptr, nullptr);
  }

  ln512<<<256, blk, 0, stream>>>(h, lnf_g, lnf_b, xn);
  if (use_wbf) {
    // Pre-convert tok_out_w to bf16 once; vocab GEMM copies W straight to LDS.
    cvt_rne<<<16000, blk, 0, stream>>>(tok_out_w, wb);
    gemm_bt<128, 128, 0, false, false, true, false, 0, true>
        <<<dim3(250, 8, 1), blk, 0, stream>>>(
        xn, (const float*)wb, tok_out_b, nullptr, out, 1024, 32000, 512, 512,
        nullptr, nullptr, nullptr);
  } else {
    gemm_bt<128, 128, 0, false, false, true, false><<<dim3(250, 8, 1), blk, 0, stream>>>(
        xn, tok_out_w, tok_out_b, nullptr, out, 1024, 32000, 512, 512,
        nullptr, nullptr, nullptr);
  }
}

// Round 5
// 1059.248 us; speedup vs baseline: 1.0550x; 1.0058x over previous
//
#include <hip/hip_runtime.h>
#include <hip/hip_bf16.h>

// SioConvNet on MI355X. Round 7: single-barrier LDS double-buffer GEMM.
//  - Per K-step: issue loads(k+1) -> fragread+MFMA on buf[cur] -> store regs
//    into buf[cur^1] (the vmcnt wait lands AFTER ~650cyc of MFMA, not before)
//    -> one __syncthreads. Round-4's variant kept 2 barriers/step and the
//    compiler's vmcnt(0)-before-barrier drained the prefetch mid-step.
//  - LDS doubles (80KB for 128x128 SPL -> 2 blocks/CU; 40KB for 64x64 and
//    vocab -> 4 blocks/CU). Measured residency was already ~2 blocks.
//  - Kept: truncation split2, bias-fold@z==0, DUAL fc/tin, WBF vocab,
//    8-block scan p1/p2/p3 with silu-in-p3.
// Split-bf16 (hi+lo, 3-pass MFMA) on every GEMM feeding the recurrence
// (za phase sensitivity amplifies bf16-level error ~100x). Vocab GEMM single bf16.
// DEPTH=3, DIM=512, DFF=2048, DT=64, VOCAB=32000, B=2, L=512, M=B*L=1024.

#define LDIM 512
#define SEQL 512
#define DT_ 64
#define NC 16
#define CL 32
#define BK 32

typedef short s16x4 __attribute__((ext_vector_type(4)));
typedef short s16x8 __attribute__((ext_vector_type(8)));
typedef float f32x4 __attribute__((ext_vector_type(4)));

__device__ __forceinline__ unsigned short f2bf(float f) {  // RNE
  unsigned u = __builtin_bit_cast(unsigned, f);
  return (unsigned short)((u + 0x7fffu + ((u >> 16) & 1u)) >> 16);
}

// Truncation split: hi = f with low mantissa zeroed; lo = trunc16(f - hi).
__device__ __forceinline__ void split2(float f, short& hi, short& lo) {
  unsigned u = __builtin_bit_cast(unsigned, f);
  hi = (short)(u >> 16);
  float hf = __builtin_bit_cast(float, u & 0xFFFF0000u);
  float lf = f - hf;  // exact
  lo = (short)(__builtin_bit_cast(unsigned, lf) >> 16);
}

// C[M,N] = act(A[M,K] @ W[N,K]^T + bias) (+R). A, W row-major, K contiguous.
// ACT: 0=none, 1=silu (post-sum). ATOM: atomicAdd into C (split-K); bias applied
// only by z==0. SPL: split-bf16 hi/lo 3-pass MFMA (fp32-class).
// AACT: 1 = silu(A) while staging. WBF: W pre-converted bf16 (shorts).
// DUAL: blockIdx.x==1 switches to (W2, bias2, C2), n0 stays 0.
template <int BM, int BN, int ACT, bool RES, bool ATOM, bool BIAS, bool SPL,
          int AACT = 0, bool WBF = false, bool DUAL = false>
__global__ __launch_bounds__(256) void gemm_bt(
    const float* __restrict__ A, const float* __restrict__ W,
    const float* __restrict__ bias, const float* __restrict__ R,
    float* __restrict__ C, int M, int N, int K, int kc,
    const float* __restrict__ W2, const float* __restrict__ bias2,
    float* __restrict__ C2) {
  constexpr int WM = BM / 2, WN = BN / 2, TM = WM / 16, TN = WN / 16;
  constexpr int LDA = BK + 8;  // rows 80B apart -> 16B-aligned, 2-way-bank (free)
  constexpr int PLANES = SPL ? 2 : 1;
  __shared__ __align__(16) short As[2][BM * LDA * PLANES];
  __shared__ __align__(16) short Bs[2][BN * LDA * PLANES];

  const int tid = threadIdx.x;
  const int wid = tid >> 6, lane = tid & 63;
  const int q = lane >> 4, l16 = lane & 15;
  const int wm = (wid >> 1) * WM, wn = (wid & 1) * WN;

  int bx = blockIdx.x, by = blockIdx.y, bz = blockIdx.z;
  if constexpr (DUAL) {
    if (bx) { W = W2; bias = bias2; C = C2; }
    bx = 0;
  }
  const int m0 = by * BM, n0 = bx * BN;
  const int kbeg = bz * kc;
  const int kend = min(K, kbeg + kc);

  f32x4 acc[TM][TN] = {};

  constexpr int AF = BM * BK / 1024;  // float4 loads per thread for A tile
  constexpr int BF = BN * BK / 1024;
  constexpr int WF = WBF ? (BN / 64) : 1;  // s16x8 loads per thread (WBF)

  float4 pa[AF];
  float4 pb[WBF ? 1 : BF];
  s16x8 pw[WF];

  auto load_a = [&](int k0) {
#pragma unroll
    for (int t = 0; t < AF; t++) {
      int fi = tid + t * 256;
      int row = fi >> 3, col = (fi & 7) << 2;
      pa[t] = *(const float4*)(A + (size_t)(m0 + row) * K + k0 + col);
    }
  };
  auto load_b = [&](int k0) {
    if constexpr (WBF) {
      const short* Wb = (const short*)W;
#pragma unroll
      for (int t = 0; t < WF; t++) {
        int fi = tid + t * 256;
        int row = fi >> 2, col8 = (fi & 3) << 3;
        pw[t] = *(const s16x8*)(Wb + (size_t)(n0 + row) * K + k0 + col8);
      }
    } else {
#pragma unroll
      for (int t = 0; t < BF; t++) {
        int fi = tid + t * 256;
        int row = fi >> 3, col = (fi & 7) << 2;
        pb[t] = *(const float4*)(W + (size_t)(n0 + row) * K + k0 + col);
      }
    }
  };
  auto store_tiles = [&](int buf) {
#pragma unroll
    for (int t = 0; t < AF; t++) {
      int fi = tid + t * 256;
      int row = fi >> 3, col = (fi & 7) << 2;
      float4 v = pa[t];
      float* vp = (float*)&v;
      s16x4 hv, lv;
#pragma unroll
      for (int c = 0; c < 4; c++) {
        if (AACT == 1) vp[c] = vp[c] / (1.f + __expf(-vp[c]));
        if (SPL) {
          short h_, l_;
          split2(vp[c], h_, l_);
          hv[c] = h_; lv[c] = l_;
        } else {
          hv[c] = (short)f2bf(vp[c]);
        }
      }
      *(s16x4*)(&As[buf][row * LDA + col]) = hv;
      if (SPL) *(s16x4*)(&As[buf][BM * LDA + row * LDA + col]) = lv;
    }
    if constexpr (WBF) {
#pragma unroll
      for (int t = 0; t < WF; t++) {
        int fi = tid + t * 256;
        int row = fi >> 2, col8 = (fi & 3) << 3;
        *(s16x8*)(&Bs[buf][row * LDA + col8]) = pw[t];
      }
    } else {
#pragma unroll
      for (int t = 0; t < BF; t++) {
        int fi = tid + t * 256;
        int row = fi >> 3, col = (fi & 7) << 2;
        float4 v = pb[t];
        const float* vp = (const float*)&v;
        s16x4 hv, lv;
#pragma unroll
        for (int c = 0; c < 4; c++) {
          if (SPL) {
            short h_, l_;
            split2(vp[c], h_, l_);
            hv[c] = h_; lv[c] = l_;
          } else {
            hv[c] = (short)f2bf(vp[c]);
          }
        }
        *(s16x4*)(&Bs[buf][row * LDA + col]) = hv;
        if (SPL) *(s16x4*)(&Bs[buf][BN * LDA + row * LDA + col]) = lv;
      }
    }
  };

  // Prologue: tile 0 into buf 0.
  load_a(kbeg);
  load_b(kbeg);
  store_tiles(0);
  __syncthreads();

  int cur = 0;
  for (int k0 = kbeg; k0 < kend; k0 += BK) {
    const bool more = (k0 + BK < kend);
    if (more) {  // issue next tile's loads; they fly under the MFMA block
      load_a(k0 + BK);
      load_b(k0 + BK);
    }
    s16x8 ah[TM], bh[TN], al[TM], bl[TN];
#pragma unroll
    for (int i = 0; i < TM; i++) {
      ah[i] = *(const s16x8*)(&As[cur][(wm + i * 16 + l16) * LDA + q * 8]);
      if (SPL) al[i] = *(const s16x8*)(&As[cur][BM * LDA + (wm + i * 16 + l16) * LDA + q * 8]);
    }
#pragma unroll
    for (int j = 0; j < TN; j++) {
      bh[j] = *(const s16x8*)(&Bs[cur][(wn + j * 16 + l16) * LDA + q * 8]);
      if (SPL) bl[j] = *(const s16x8*)(&Bs[cur][BN * LDA + (wn + j * 16 + l16) * LDA + q * 8]);
    }
#pragma unroll
    for (int i = 0; i < TM; i++)
#pragma unroll
      for (int j = 0; j < TN; j++) {
        acc[i][j] = __builtin_amdgcn_mfma_f32_16x16x32_bf16(ah[i], bh[j], acc[i][j], 0, 0, 0);
        if (SPL) {
          acc[i][j] = __builtin_amdgcn_mfma_f32_16x16x32_bf16(ah[i], bl[j], acc[i][j], 0, 0, 0);
          acc[i][j] = __builtin_amdgcn_mfma_f32_16x16x32_bf16(al[i], bh[j], acc[i][j], 0, 0, 0);
        }
      }
    if (more) {
      store_tiles(cur ^ 1);  // vmcnt wait for the prefetch lands here, post-MFMA
      __syncthreads();
      cur ^= 1;
    }
  }

#pragma unroll
  for (int i = 0; i < TM; i++)
#pragma unroll
    for (int j = 0; j < TN; j++)
#pragma unroll
      for (int r = 0; r < 4; r++) {
        int m = m0 + wm + i * 16 + q * 4 + r;
        int n = n0 + wn + j * 16 + l16;
        float v = acc[i][j][r];
        if (BIAS && kbeg == 0) v += bias[n];
        if (ACT == 1) v = v / (1.f + __expf(-v));
        if (RES) v += R[(size_t)m * N + n];
        if (ATOM) atomicAdd(&C[(size_t)m * N + n], v);
        else C[(size_t)m * N + n] = v;
      }
}

// Zero-fill (count divisible by 1024).
__global__ __launch_bounds__(256) void fill0(float* __restrict__ p) {
  size_t i = (size_t)(blockIdx.x * 256 + threadIdx.x) * 4;
  *(float4*)(p + i) = make_float4(0.f, 0.f, 0.f, 0.f);
}

// fp32 -> bf16 (RNE) streaming convert, 4 elems/thread.
__global__ __launch_bounds__(256) void cvt_rne(const float* __restrict__ src,
                                               short* __restrict__ dst) {
  size_t i = (size_t)(blockIdx.x * 256 + threadIdx.x) * 4;
  float4 v = *(const float4*)(src + i);
  const float* vp = (const float*)&v;
  s16x4 o;
#pragma unroll
  for (int c = 0; c < 4; c++) o[c] = (short)f2bf(vp[c]);
  *(s16x4*)(dst + i) = o;
}

// LayerNorm over last dim 512; one wave per row.
__global__ __launch_bounds__(256) void ln512(const float* __restrict__ x,
                                             const float* __restrict__ g,
                                             const float* __restrict__ b,
                                             float* __restrict__ o) {
  int wid = threadIdx.x >> 6, lane = threadIdx.x & 63;
  int row = blockIdx.x * 4 + wid;
  const float* xr = x + (size_t)row * 512 + lane * 8;
  float4 v0 = *(const float4*)xr;
  float4 v1 = *(const float4*)(xr + 4);
  float s = v0.x + v0.y + v0.z + v0.w + v1.x + v1.y + v1.z + v1.w;
  float ss = v0.x * v0.x + v0.y * v0.y + v0.z * v0.z + v0.w * v0.w +
             v1.x * v1.x + v1.y * v1.y + v1.z * v1.z + v1.w * v1.w;
#pragma unroll
  for (int m = 32; m; m >>= 1) { s += __shfl_xor(s, m); ss += __shfl_xor(ss, m); }
  float mean = s * (1.f / 512.f);
  float var = ss * (1.f / 512.f) - mean * mean;
  float rstd = rsqrtf(var + 1e-5f);
  const float* gp = g + lane * 8;
  const float* bp = b + lane * 8;
  float4 g0 = *(const float4*)gp, g1 = *(const float4*)(gp + 4);
  float4 b0 = *(const float4*)bp, b1 = *(const float4*)(bp + 4);
  float* op = o + (size_t)row * 512 + lane * 8;
  float4 r0, r1;
  r0.x = (v0.x - mean) * rstd * g0.x + b0.x;
  r0.y = (v0.y - mean) * rstd * g0.y + b0.y;
  r0.z = (v0.z - mean) * rstd * g0.z + b0.z;
  r0.w = (v0.w - mean) * rstd * g0.w + b0.w;
  r1.x = (v1.x - mean) * rstd * g1.x + b1.x;
  r1.y = (v1.y - mean) * rstd * g1.y + b1.y;
  r1.z = (v1.z - mean) * rstd * g1.z + b1.z;
  r1.w = (v1.w - mean) * rstd * g1.w + b1.w;
  *(float4*)op = r0;
  *(float4*)(op + 4) = r1;
}

// a[b,i,d] from za: a = za * rsqrt(|za|^2) * exp(-|za|^2)
__device__ __forceinline__ float2 a_of(const float* __restrict__ za, int b, int i, int d) {
  float zr = za[(size_t)(b * SEQL + i) * 128 + 2 * d];
  float zi = za[(size_t)(b * SEQL + i) * 128 + 2 * d + 1];
  float m2 = zr * zr + zi * zi;
  float sc = rsqrtf(m2) * __expf(-m2);
  return make_float2(zr * sc, zi * sc);
}

// xsm1[i]: 0 for i==0, h0c for i==1, u[i-2] (real) otherwise.
__device__ __forceinline__ float2 xsm1_of(const float* __restrict__ u,
                                          const float* __restrict__ h0,
                                          int b, int i, int d) {
  if (i == 0) return make_float2(0.f, 0.f);
  if (i == 1) return make_float2(h0[d * 2], h0[d * 2 + 1]);
  return make_float2(u[(size_t)(b * SEQL + i - 2) * DT_ + d], 0.f);
}

// Phase 1: per (b,d,chunk): A = prod a[i], Bv = backward eval with t_end=0.
__global__ __launch_bounds__(256) void scan_p1(const float* __restrict__ za,
                                               const float* __restrict__ u,
                                               const float* __restrict__ h0,
                                               float2* __restrict__ cA,
                                               float2* __restrict__ cB) {
  int tid = blockIdx.x * 256 + threadIdx.x;  // 2048 = B*NC*D, d fastest
  int d = tid & 63, c = (tid >> 6) & (NC - 1), b = tid >> 10;
  float2 Aa = make_float2(1.f, 0.f), Bv = make_float2(0.f, 0.f);
  for (int i = c * CL + CL - 1; i >= c * CL; i--) {
    float2 a = a_of(za, b, i, d);
    float2 xs = xsm1_of(u, h0, b, i, d);
    float2 nb, nA;
    nb.x = xs.x + a.x * Bv.x - a.y * Bv.y;
    nb.y = xs.y + a.x * Bv.y + a.y * Bv.x;
    nA.x = a.x * Aa.x - a.y * Aa.y;
    nA.y = a.x * Aa.y + a.y * Aa.x;
    Bv = nb; Aa = nA;
  }
  cA[tid] = Aa;
  cB[tid] = Bv;
}

// Phase 2: backward combine over the NC chunks, store t at each chunk end.
__global__ __launch_bounds__(128) void scan_p2(const float* __restrict__ u,
                                               const float2* __restrict__ cA,
                                               const float2* __restrict__ cB,
                                               float2* __restrict__ tE) {
  int tid = threadIdx.x;  // 128 = B*D
  int d = tid & 63, b = tid >> 6;
  float2 t = make_float2(u[(size_t)(b * SEQL + SEQL - 2) * DT_ + d], 0.f);  // t[L]=xs[L-1]
  for (int c = NC - 1; c >= 0; c--) {
    int idx = (b << 10) + (c << 6) + d;
    tE[idx] = t;
    float2 A = cA[idx], Bv = cB[idx];
    float2 nt;
    nt.x = A.x * t.x - A.y * t.y + Bv.x;
    nt.y = A.x * t.y + A.y * t.x + Bv.y;
    t = nt;
  }
}

// Phase 3: redo chunk backward scan from known t_end; p = real(h) * silu(y).
// (y arrives PRE-activation.)
__global__ __launch_bounds__(256) void scan_p3(const float* __restrict__ za,
                                               const float* __restrict__ u,
                                               const float* __restrict__ h0,
                                               const float* __restrict__ y,
                                               const float2* __restrict__ tE,
                                               float* __restrict__ p) {
  int tid = blockIdx.x * 256 + threadIdx.x;
  int d = tid & 63, c = (tid >> 6) & (NC - 1), b = tid >> 10;
  float2 t = tE[tid];
  for (int i = c * CL + CL - 1; i >= c * CL; i--) {
    float2 a = a_of(za, b, i, d);
    float2 xs = xsm1_of(u, h0, b, i, d);
    float2 nt;
    nt.x = xs.x + a.x * t.x - a.y * t.y;
    nt.y = xs.y + a.x * t.y + a.y * t.x;
    t = nt;
    float hr = t.x;
    if (i == SEQL - 1) hr += u[(size_t)(b * SEQL + SEQL - 1) * DT_ + d];
    size_t o = (size_t)(b * SEQL + i) * DT_ + d;
    float yv = y[o];
    yv = yv / (1.f + __expf(-yv));
    p[o] = hr * yv;
  }
}

extern "C" void kernel_launch(void* const* d_in, const int* in_sizes, int n_in,
                              void* d_out, int out_size, void* d_ws, size_t ws_size,
                              hipStream_t stream) {
  const float* x        = (const float*)d_in[0];
  const float* tok_in_w = (const float*)d_in[1];
  const float* tok_in_b = (const float*)d_in[2];
  const float* ln1_g    = (const float*)d_in[3];
  const float* ln1_b    = (const float*)d_in[4];
  const float* fc_w     = (const float*)d_in[5];
  const float* fc_b     = (const float*)d_in[6];
  const float* tin_w    = (const float*)d_in[7];
  const float* tin_b    = (const float*)d_in[8];
  const float* a_w      = (const float*)d_in[9];
  const float* h0       = (const float*)d_in[10];
  const float* tout_w   = (const float*)d_in[11];
  const float* tout_b   = (const float*)d_in[12];
  const float* ln2_g    = (const float*)d_in[13];
  const float* ln2_b    = (const float*)d_in[14];
  const float* ffn_w1   = (const float*)d_in[15];
  const float* ffn_b1   = (const float*)d_in[16];
  const float* ffn_w2   = (const float*)d_in[17];
  const float* ffn_b2   = (const float*)d_in[18];
  const float* lnf_g    = (const float*)d_in[19];
  const float* lnf_b    = (const float*)d_in[20];
  const float* tok_out_w = (const float*)d_in[21];
  const float* tok_out_b = (const float*)d_in[22];
  float* out = (float*)d_out;

  float* ws = (float*)d_ws;
  float* h  = ws;                 // 1024*512
  float* xn = h + 524288;         // 1024*512
  float* y  = xn + 524288;        // 1024*64   (y,u contiguous: one fill0)
  float* u  = y + 65536;          // 1024*64
  float* za = u + 65536;          // 1024*128
  float* p  = za + 131072;        // 1024*64
  float* f1 = p + 65536;          // 1024*2048
  float2* cA = (float2*)(f1 + 2097152);  // 2048
  float2* cB = cA + 2048;
  float2* tE = cB + 2048;
  short* wb = (short*)(tE + 2048);  // 32000*512 bf16 = 8192000 float-slots
  const bool use_wbf = ws_size >= (size_t)(3485696 + 8192000) * 4;

  dim3 blk(256);

  // h = x @ tok_in_w.T + tok_in_b. Split-K z=32 (1024 blocks), bias at z==0.
  fill0<<<512, blk, 0, stream>>>(h);
  gemm_bt<128, 128, 0, false, true, true, true><<<dim3(4, 8, 32), blk, 0, stream>>>(
      x, tok_in_w, tok_in_b, nullptr, h, 1024, 512, 32000, 1024,
      nullptr, nullptr, nullptr);

  for (int l = 0; l < 3; l++) {
    ln512<<<256, blk, 0, stream>>>(h, ln1_g + l * 512, ln1_b + l * 512, xn);
    // y,u zero in one pass (contiguous 131072 floats).
    fill0<<<128, blk, 0, stream>>>(y);
    // fc+tin merged: bx=0 -> y=xn@fc_w.T+fc_b (pre-act, silu in scan_p3);
    // bx=1 -> u=xn@tin_w.T+tin_b. 64x64 tiles, z=4 -> 128 blocks.
    gemm_bt<64, 64, 0, false, true, true, true, 0, false, true>
        <<<dim3(2, 16, 4), blk, 0, stream>>>(
        xn, fc_w + l * 32768, fc_b + l * 64, nullptr, y, 1024, 64, 512, 128,
        tin_w + l * 32768, tin_b + l * 64, u);
    // za = u @ a_w.T. 64x64 tiles -> 32 blocks.
    gemm_bt<64, 64, 0, false, false, false, true><<<dim3(2, 16, 1), blk, 0, stream>>>(
        u, a_w + l * 8192, nullptr, nullptr, za, 1024, 128, 64, 64,
        nullptr, nullptr, nullptr);
    scan_p1<<<8, blk, 0, stream>>>(za, u, h0 + l * 128, cA, cB);
    scan_p2<<<1, 128, 0, stream>>>(u, cA, cB, tE);
    scan_p3<<<8, blk, 0, stream>>>(za, u, h0 + l * 128, y, tE, p);
    // tout: h = p @ tout_w.T + tout_b + h. 64x128 tiles -> 64 blocks.
    gemm_bt<64, 128, 0, true, false, true, true><<<dim3(4, 16, 1), blk, 0, stream>>>(
        p, tout_w + l * 32768, tout_b + l * 512, h, h, 1024, 512, 64, 64,
        nullptr, nullptr, nullptr);
    ln512<<<256, blk, 0, stream>>>(h, ln2_g + l * 512, ln2_b + l * 512, xn);
    // ffn1: f1 = xn @ w1.T + b1 (pre-act). z=2 -> 256 blocks.
    fill0<<<2048, blk, 0, stream>>>(f1);
    gemm_bt<128, 128, 0, false, true, true, true><<<dim3(16, 8, 2), blk, 0, stream>>>(
        xn, ffn_w1 + l * 1048576, ffn_b1 + l * 2048, nullptr, f1, 1024, 2048, 512, 256,
        nullptr, nullptr, nullptr);
    // ffn2: h += silu(f1) @ w2.T + b2. z=8 -> 256 blocks, silu on A-staging,
    // bias at z==0, residual already in h.
    gemm_bt<128, 128, 0, false, true, true, true, 1><<<dim3(4, 8, 8), blk, 0, stream>>>(
        f1, ffn_w2 + l * 1048576, ffn_b2 + l * 512, nullptr, h, 1024, 512, 2048, 256,
        nullptr, nullptr, nullptr);
  }

  ln512<<<256, blk, 0, stream>>>(h, lnf_g, lnf_b, xn);
  if (use_wbf) {
    // Pre-convert tok_out_w to bf16 once; vocab GEMM copies W straight to LDS.
    cvt_rne<<<16000, blk, 0, stream>>>(tok_out_w, wb);
    gemm_bt<128, 128, 0, false, false, true, false, 0, true>
        <<<dim3(250, 8, 1), blk, 0, stream>>>(
        xn, (const float*)wb, tok_out_b, nullptr, out, 1024, 32000, 512, 512,
        nullptr, nullptr, nullptr);
  } else {
    gemm_bt<128, 128, 0, false, false, true, false><<<dim3(250, 8, 1), blk, 0, stream>>>(
        xn, tok_out_w, tok_out_b, nullptr, out, 1024, 32000, 512, 512,
        nullptr, nullptr, nullptr);
  }
}